// Round 8
// baseline (1755.382 us; speedup 1.0000x reference)
//
#include <hip/hip_runtime.h>
#include <stdint.h>

// genericPINN v7: SPB=32 via single 1024-thread block (16 waves, 4/SIMD, 1 block/CU).
// Weight stream halved to 8 GiB L2-volume; B staged per-block into LDS dbuf via
// global_load_lds with counted vmcnt(1) (T3/T4), ds_reads of group g consumed by
// MFMAs in slot g+1 (loads overlap MFMA between barriers). A = 128KB tiled
// conflict-free layout; LDS = 128K A + 2x16K B = 160 KiB exactly.
// (Resubmission #2: rounds 6 and 7 both failed with GPUAcquisitionTimeout.)

#define B_SZ   65536
#define NN     512
#define NL     8
#define SPB    32            // samples per block
#define MROWS  128           // 4 * SPB stream-rows
#define NKS    32            // K-steps of 16 per layer
#define NG2    (NL*NKS)      // 256 weight groups of 16 KiB
#define LDS_AA (MROWS*1024)  // 131072 = 32 k-tiles x 4096 B
#define BBUF   16384
#define LDS_TOTAL (LDS_AA + 2*BBUF)   // 163840 = full 160 KiB

typedef _Float16 f16x8  __attribute__((ext_vector_type(8)));
typedef float    f32x16 __attribute__((ext_vector_type(16)));

__device__ __forceinline__ uint16_t f2h_bits(float f) {
  union { _Float16 h; uint16_t u; } v; v.h = (_Float16)f; return v.u;
}
__device__ __forceinline__ float h2f(uint16_t b) {
  union { uint16_t u; _Float16 h; } v; v.u = b; return (float)v.h;
}

// A element (m,k) byte offset: tile=k>>4 (stride 4096), khp=(k>>3)&1 (stride 2048),
// m' = m ^ (khp<<2) ^ ((tile&1)<<1), e=k&7
__device__ __forceinline__ int abyte(int m, int k) {
  const int tile = k >> 4, khp = (k >> 3) & 1, e = k & 7;
  const int mp = m ^ (khp << 2) ^ ((tile & 1) << 1);
  return (tile << 12) + (khp << 11) + (mp << 4) + (e << 1);
}

// ---- prep: Ws (L,512,512) fp32 -> f16 image, 16KB groups g2 = l*32+ks.
// [sub = wc*2 + Nt][lane][16B]; frag: W[ks*16+(lane>>5)*8+e][wc*64+Nt*32+(lane&31)]
__global__ __launch_bounds__(512) void prep_weights(const float* __restrict__ Ws,
                                                    uint16_t* __restrict__ img) {
  const int g2 = blockIdx.x;              // 0..255
  const int l  = g2 >> 5, ks = g2 & 31;
  const float* src = Ws + ((size_t)l << 18);
  char* dst = (char*)img + ((size_t)g2 << 14);
  #pragma unroll
  for (int it = 0; it < 2; ++it) {
    const int fidx = threadIdx.x + it*512;          // 0..1023 fragments
    const int ln  = fidx & 63, sub = fidx >> 6;
    const int n     = (sub >> 1)*64 + (sub & 1)*32 + (ln & 31);
    const int kbase = ks*16 + (ln >> 5)*8;
    uint16_t h[8];
    #pragma unroll
    for (int e = 0; e < 8; ++e)
      h[e] = f2h_bits(src[(size_t)(kbase + e)*512 + n]);
    uint4 pk;
    pk.x = (uint32_t)h[0] | ((uint32_t)h[1] << 16);
    pk.y = (uint32_t)h[2] | ((uint32_t)h[3] << 16);
    pk.z = (uint32_t)h[4] | ((uint32_t)h[5] << 16);
    pk.w = (uint32_t)h[6] | ((uint32_t)h[7] << 16);
    *(uint4*)(dst + (size_t)fidx*16) = pk;
  }
}

__global__ __launch_bounds__(1024, 4) void pinn_fused(
    const float* __restrict__ inputs, const float* __restrict__ Brff,
    const float* __restrict__ bs, const float* __restrict__ alphas,
    const float* __restrict__ Wf, const float* __restrict__ scl,
    const uint16_t* __restrict__ wimg, float* __restrict__ out)
{
  extern __shared__ char smem[];

  const int tid  = threadIdx.x;
  const int lane = tid & 63;
  const int wv   = tid >> 6;        // wave 0..15
  const int wr   = wv >> 3;         // row half (0/1)
  const int wc   = wv & 7;          // col group
  const int l31  = lane & 31;
  const int kh   = lane >> 5;       // k-half (0/1)
  const int sbase = blockIdx.x * SPB;   // 2048 * 32 == 65536

  char* bbuf0 = smem + LDS_AA;
  char* bbuf1 = bbuf0 + BBUF;

  // stage one 16KB weight group into an LDS buffer (1 DMA per thread)
  auto stage = [&](int g2, char* bb) {
    const char* src = (const char*)wimg + ((size_t)g2 << 14)
                    + ((size_t)wv << 10) + (size_t)lane * 16;
    __builtin_amdgcn_global_load_lds(
        (const __attribute__((address_space(1))) void*)src,
        (__attribute__((address_space(3))) void*)(bb + (wv << 10)), 16, 0, 0);
  };

  stage(0, bbuf0);      // prologue: prime the pipeline (hides under layer 0)
  stage(1, bbuf1);

  // ---- layer 0: u0 = [sin z, cos z]; du0_c = [cos z * B_c, -sin z * B_c] ----
  {
    const int k = tid & 511, sh = tid >> 9, col = k & 255;
    const bool iscos = (k >= 256);
    const float b0 = Brff[col];
    const float b1 = Brff[256 + col];
    const float b2 = Brff[512 + col];
    const float b3 = Brff[768 + col];
    const int cb = ((k >> 4) << 12) + (((k >> 3) & 1) << 11) + ((k & 7) << 1);
    const int xm = (((k >> 3) & 1) << 2) ^ (((k >> 4) & 1) << 1);
    for (int ss = 0; ss < SPB/2; ++ss) {
      const int s = sh*(SPB/2) + ss;
      const float4 x = *(const float4*)(inputs + ((size_t)(sbase + s) << 2));
      const float z = x.x*b0 + x.y*b1 + x.z*b2 + x.w*b3;
      const float szn = __sinf(z), czn = __cosf(z);
      const float u0 = iscos ? czn : szn;
      const float dz = iscos ? -szn : czn;
      const int m0 = 4*s;
      *(uint16_t*)(smem + cb + (((m0+0) ^ xm) << 4)) = f2h_bits(u0);
      *(uint16_t*)(smem + cb + (((m0+1) ^ xm) << 4)) = f2h_bits(dz*b1);
      *(uint16_t*)(smem + cb + (((m0+2) ^ xm) << 4)) = f2h_bits(dz*b2);
      *(uint16_t*)(smem + cb + (((m0+3) ^ xm) << 4)) = f2h_bits(dz*b3);
    }
  }
  __syncthreads();

  // per-lane fixed addresses
  const int bro = wc*2048 + lane*16;                              // B frag in buffer
  const int aoE = (kh << 11) + (((wr << 6) + (l31 ^ (kh << 2))) << 4);
  const char* paE = smem + aoE;          // even k-tile A frag base
  const char* paO = smem + (aoE ^ 32);   // odd k-tile (row^2 -> byte^32)

  f16x8 aE0, aE1, aO0, aO1, bE0, bE1, bO0, bO1;
  const f32x16 zz = {0,0,0,0,0,0,0,0,0,0,0,0,0,0,0,0};
  f32x16 a00, a01, a10, a11;

#define MFMAQ(x0, x1, y0, y1) do {                                         \
    __builtin_amdgcn_s_setprio(1);                                         \
    a00 = __builtin_amdgcn_mfma_f32_32x32x16_f16(x0, y0, a00, 0, 0, 0);    \
    a01 = __builtin_amdgcn_mfma_f32_32x32x16_f16(x0, y1, a01, 0, 0, 0);    \
    a10 = __builtin_amdgcn_mfma_f32_32x32x16_f16(x1, y0, a10, 0, 0, 0);    \
    a11 = __builtin_amdgcn_mfma_f32_32x32x16_f16(x1, y1, a11, 0, 0, 0);    \
    __builtin_amdgcn_s_setprio(0);                                         \
  } while (0)

  for (int l = 0; l < NL; ++l) {
    a00 = zz; a01 = zz; a10 = zz; a11 = zz;
    const int g2b = l << 5;
    int atile = 0;

    #pragma unroll 1
    for (int t = 0; t < NKS/2; ++t) {
      // ---- ks = 2t (even, buffer 0) ----
      {
        asm volatile("s_waitcnt vmcnt(1)" ::: "memory");   // group 2t staged
        __builtin_amdgcn_s_barrier();                      // visible to all waves
        __builtin_amdgcn_sched_barrier(0);
        bE0 = *(const f16x8*)(bbuf0 + bro);
        bE1 = *(const f16x8*)(bbuf0 + bro + 1024);
        aE0 = *(const f16x8*)(paE + atile);
        aE1 = *(const f16x8*)(paE + atile + 512);
        if (t) MFMAQ(aO0, aO1, bO0, bO1);                  // group 2t-1 (prev regs)
        asm volatile("s_waitcnt lgkmcnt(0)" ::: "memory"); // my buf0 reads done
        __builtin_amdgcn_s_barrier();                      // everyone's reads done
        __builtin_amdgcn_sched_barrier(0);
        int gs = g2b + 2*t + 2; if (gs > NG2-1) gs = NG2-1;
        stage(gs, bbuf0);                                  // refill buffer 0
      }
      // ---- ks = 2t+1 (odd, buffer 1) ----
      {
        asm volatile("s_waitcnt vmcnt(1)" ::: "memory");
        __builtin_amdgcn_s_barrier();
        __builtin_amdgcn_sched_barrier(0);
        bO0 = *(const f16x8*)(bbuf1 + bro);
        bO1 = *(const f16x8*)(bbuf1 + bro + 1024);
        aO0 = *(const f16x8*)(paO + atile + 4096);
        aO1 = *(const f16x8*)(paO + atile + 4096 + 512);
        MFMAQ(aE0, aE1, bE0, bE1);                         // group 2t
        asm volatile("s_waitcnt lgkmcnt(0)" ::: "memory");
        __builtin_amdgcn_s_barrier();
        __builtin_amdgcn_sched_barrier(0);
        int gs = g2b + 2*t + 3; if (gs > NG2-1) gs = NG2-1;
        stage(gs, bbuf1);                                  // refill buffer 1
      }
      atile += 8192;
    }
    MFMAQ(aO0, aO1, bO0, bO1);                             // drain ks = 31

    // ---- epilogue: h=(1+a)(dot+b); u'=sin h; du'=(1+a)cos(h)*dot_t ----
    // 32x32 C/D layout: col = lane&31, row = (r&3) + 8*(r>>2) + 4*(lane>>5)
    const float opa = 1.0f + alphas[l];
    #pragma unroll
    for (int Nt = 0; Nt < 2; ++Nt) {
      const int nc = wc*64 + Nt*32 + l31;
      const int cb = ((nc >> 4) << 12) + (((nc >> 3) & 1) << 11) + ((nc & 7) << 1);
      const int xm = (((nc >> 3) & 1) << 2) ^ (((nc >> 4) & 1) << 1);
      const float bias = bs[l*NN + nc];
      #pragma unroll
      for (int Mt = 0; Mt < 2; ++Mt) {
        const f32x16 c = (Mt == 0) ? (Nt == 0 ? a00 : a01)
                                   : (Nt == 0 ? a10 : a11);
        #pragma unroll
        for (int j = 0; j < 4; ++j) {
          const float hh = opa * (c[4*j] + bias);
          const float un = __sinf(hh);
          const float fc = opa * __cosf(hh);
          const float vv[4] = { un, fc*c[4*j+1], fc*c[4*j+2], fc*c[4*j+3] };
          const int m0 = wr*64 + Mt*32 + 8*j + 4*kh;
          #pragma unroll
          for (int s = 0; s < 4; ++s) {
            const int m = m0 + s;
            *(uint16_t*)(smem + cb + ((m ^ xm) << 4)) = f2h_bits(vv[s]);
          }
        }
      }
    }
    asm volatile("s_waitcnt lgkmcnt(0)" ::: "memory");  // my A-writes done before
                                                        // next layer's top barrier
  }

  // kill leftover staging DMAs before overlaying dp onto buffer 0
  asm volatile("s_waitcnt vmcnt(0)" ::: "memory");
  __syncthreads();

  // ---- final projection: dp[m][o] = sum_k A[m][k]*Wf[k][o] * scale[o] ----
  float* dp = (float*)bbuf0;
  const float4 sc4 = *(const float4*)scl;
  for (int rr = 0; rr < 8; ++rr) {          // 8 rows per wave, 16 waves = 128 rows
    const int m = wv*8 + rr;
    float p0 = 0.f, p1 = 0.f, p2 = 0.f, p3 = 0.f;
    #pragma unroll
    for (int j = 0; j < 8; ++j) {
      const int k = lane + j*64;
      float a = h2f(*(const uint16_t*)(smem + abyte(m, k)));
      float4 wf = ((const float4*)Wf)[k];
      p0 += a*wf.x; p1 += a*wf.y; p2 += a*wf.z; p3 += a*wf.w;
    }
    #pragma unroll
    for (int d = 1; d < 64; d <<= 1) {
      p0 += __shfl_xor(p0, d, 64);
      p1 += __shfl_xor(p1, d, 64);
      p2 += __shfl_xor(p2, d, 64);
      p3 += __shfl_xor(p3, d, 64);
    }
    if (lane == 0) {
      float4* o = (float4*)(dp + m*4);
      *o = make_float4(p0*sc4.x, p1*sc4.y, p2*sc4.z, p3*sc4.w);
    }
  }
  __syncthreads();

  // rows 4s+1=dPdz, 4s+2=dPdx, 4s+3=dPdy
  // u = dPdy[2]-dPdz[1]+dPdx[3]; v = dPdz[0]-dPdx[2]+dPdy[3]; w = dPdx[1]-dPdy[0]+dPdz[3]
  if (tid < SPB*3) {
    const int sl = tid / 3, c = tid - sl*3;
    const float* d1 = dp + (sl*4 + 1)*4;
    const float* d2 = dp + (sl*4 + 2)*4;
    const float* d3 = dp + (sl*4 + 3)*4;
    float val;
    if (c == 0)      val = d3[2] - d1[1] + d2[3];
    else if (c == 1) val = d1[0] - d2[2] + d3[3];
    else             val = d2[1] - d3[0] + d1[3];
    out[(size_t)(sbase + sl)*3 + c] = val;
  }
}

extern "C" void kernel_launch(void* const* d_in, const int* in_sizes, int n_in,
                              void* d_out, int out_size, void* d_ws, size_t ws_size,
                              hipStream_t stream) {
  const float* inputs = (const float*)d_in[0];
  const float* Brff   = (const float*)d_in[1];
  const float* Ws     = (const float*)d_in[2];
  const float* bsp    = (const float*)d_in[3];
  const float* alph   = (const float*)d_in[4];
  const float* Wfp    = (const float*)d_in[5];
  const float* sclp   = (const float*)d_in[6];
  uint16_t* wimg = (uint16_t*)d_ws;           // needs 4 MiB workspace

  prep_weights<<<NG2, 512, 0, stream>>>(Ws, wimg);
  const int nblocks = B_SZ / SPB;             // 2048
  pinn_fused<<<nblocks, 1024, LDS_TOTAL, stream>>>(inputs, Brff, bsp, alph, Wfp, sclp,
                                                   wimg, (float*)d_out);
}

// Round 11
// 1362.604 us; speedup vs baseline: 1.2883x; 1.2883x over previous
//
#include <hip/hip_runtime.h>
#include <stdint.h>

// genericPINN v8: v3 (best measured, 1343us) + per-wave cyclic K-rotation
// (ksr = wv*4): waves of a block sweep the 32 K-steps in rotated order so their
// load/LDS/MFMA phases decorrelate (convoy-break). K-sum is order-independent.
// Geometry unchanged: SPB=16, 8 waves x (64 rows x 64 cols), 32x32x16 f16 MFMA,
// reg dbuf A+B, 2 blocks/CU (16 waves/CU).
// (Resubmission #3: rounds 9 and 10 failed with GPUAcquisitionTimeout.)

#define B_SZ   65536
#define NN     512
#define NL     8
#define SPB    16            // samples per block
#define MROWS  64            // 4 * SPB stream-rows
#define NKS    32            // K-steps of 16 per layer
#define NG2    (NL*NKS)      // 256 weight groups of 16 KiB
#define LDS_A  (MROWS*1024)  // 65536
#define LDS_TOTAL (LDS_A + 1024)

typedef _Float16 f16x8  __attribute__((ext_vector_type(8)));
typedef float    f32x16 __attribute__((ext_vector_type(16)));

__device__ __forceinline__ uint16_t f2h_bits(float f) {
  union { _Float16 h; uint16_t u; } v; v.h = (_Float16)f; return v.u;
}
__device__ __forceinline__ float h2f(uint16_t b) {
  union { uint16_t u; _Float16 h; } v; v.u = b; return (float)v.h;
}

// ---- prep: Ws (L,512,512) fp32 -> f16 image for per-wave 32x32x16 B-frag reg loads.
// img[g2][wv][Nt][lane][16B], g2 = l*32 + ks  (16 KiB per group).
// frag for lane: W[ks*16 + (lane>>5)*8 + e][wv*64 + Nt*32 + (lane&31)], e=0..7
__global__ __launch_bounds__(512) void prep_weights(const float* __restrict__ Ws,
                                                    uint16_t* __restrict__ img) {
  const int g2 = blockIdx.x;              // 0..255
  const int l  = g2 >> 5, ks = g2 & 31;
  const float* src = Ws + ((size_t)l << 18);
  char* dst = (char*)img + ((size_t)g2 << 14);
  #pragma unroll
  for (int it = 0; it < 2; ++it) {
    const int fidx = threadIdx.x + it*512;          // 0..1023 fragments
    const int ln  = fidx & 63, sub = fidx >> 6;     // sub = wv*2 + Nt
    const int n     = (sub >> 1)*64 + (sub & 1)*32 + (ln & 31);
    const int kbase = ks*16 + (ln >> 5)*8;
    uint16_t h[8];
    #pragma unroll
    for (int e = 0; e < 8; ++e)
      h[e] = f2h_bits(src[(size_t)(kbase + e)*512 + n]);
    uint4 pk;
    pk.x = (uint32_t)h[0] | ((uint32_t)h[1] << 16);
    pk.y = (uint32_t)h[2] | ((uint32_t)h[3] << 16);
    pk.z = (uint32_t)h[4] | ((uint32_t)h[5] << 16);
    pk.w = (uint32_t)h[6] | ((uint32_t)h[7] << 16);
    *(uint4*)(dst + (size_t)fidx*16) = pk;
  }
}

__global__ __launch_bounds__(512, 4) void pinn_fused(
    const float* __restrict__ inputs, const float* __restrict__ Brff,
    const float* __restrict__ bs, const float* __restrict__ alphas,
    const float* __restrict__ Wf, const float* __restrict__ scl,
    const uint16_t* __restrict__ wimg, float* __restrict__ out)
{
  extern __shared__ char smem[];

  const int tid  = threadIdx.x;
  const int lane = tid & 63;
  const int wv   = tid >> 6;        // wave 0..7
  const int l31  = lane & 31;
  const int kh   = lane >> 5;       // k-half (0/1)
  const int ksr  = wv << 2;         // per-wave K-rotation (0,4,...,28)
  const int sbase = blockIdx.x * SPB;   // 4096 * 16 == 65536

  // per-wave weight stream base: + G*16384 below
  const char* wb = (const char*)wimg + ((size_t)(wv*2) << 10) + (size_t)lane*16;

  f16x8 bfA0, bfA1, bfB0, bfB1;
  // initial B prefetch for sequence positions 0,1 of layer 0 (rotated groups)
  {
    const int G0 = ksr;
    const int G1 = (ksr + 1) & 31;
    const char* p0 = wb + ((size_t)G0 << 14);
    const char* p1 = wb + ((size_t)G1 << 14);
    bfA0 = *(const f16x8*)(p0);
    bfA1 = *(const f16x8*)(p0 + 1024);
    bfB0 = *(const f16x8*)(p1);
    bfB1 = *(const f16x8*)(p1 + 1024);
  }

  // ---- layer 0: u0 = [sin z, cos z]; du0_c = [cos z * B_c, -sin z * B_c] ----
  {
    const int k = tid, col = k & 255;
    const bool iscos = (k >= 256);
    const float b0 = Brff[col];
    const float b1 = Brff[256 + col];
    const float b2 = Brff[512 + col];
    const float b3 = Brff[768 + col];
    const int koff = 2*k;
    for (int s = 0; s < SPB; ++s) {
      const float4 x = *(const float4*)(inputs + ((size_t)(sbase + s) << 2));
      const float z = x.x*b0 + x.y*b1 + x.z*b2 + x.w*b3;
      const float szn = __sinf(z), czn = __cosf(z);
      const float u0 = iscos ? czn : szn;
      const float dz = iscos ? -szn : czn;
      const int m0 = 4*s;
      *(uint16_t*)(smem + (size_t)(m0+0)*1024 + (koff ^ (((m0+0) & 7)*16))) = f2h_bits(u0);
      *(uint16_t*)(smem + (size_t)(m0+1)*1024 + (koff ^ (((m0+1) & 7)*16))) = f2h_bits(dz*b1);
      *(uint16_t*)(smem + (size_t)(m0+2)*1024 + (koff ^ (((m0+2) & 7)*16))) = f2h_bits(dz*b2);
      *(uint16_t*)(smem + (size_t)(m0+3)*1024 + (koff ^ (((m0+3) & 7)*16))) = f2h_bits(dz*b3);
    }
  }
  __syncthreads();

  // ---- A-frag addressing (rows m = Mt*32 + l31, k byte col = kk*32 + kh*16) ----
  const int rx   = (l31 & 7) * 16;       // row swizzle (Mt*32 doesn't change m&7)
  const int hoff = kh * 16;
  char* arow0 = smem + (size_t)l31 * 1024;
  char* arow1 = arow0 + 32*1024;

  const int co0 = ((ksr << 5) + hoff) ^ rx;   // sequence position 0

  f16x8 afA0, afA1, afB0, afB1;
  afA0 = *(const f16x8*)(arow0 + co0);
  afA1 = *(const f16x8*)(arow1 + co0);

  const f32x16 zz = {0,0,0,0,0,0,0,0,0,0,0,0,0,0,0,0};

#define MFMAQ(x0, x1, y0, y1) do {                                         \
    __builtin_amdgcn_s_setprio(1);                                         \
    a00 = __builtin_amdgcn_mfma_f32_32x32x16_f16(x0, y0, a00, 0, 0, 0);    \
    a01 = __builtin_amdgcn_mfma_f32_32x32x16_f16(x0, y1, a01, 0, 0, 0);    \
    a10 = __builtin_amdgcn_mfma_f32_32x32x16_f16(x1, y0, a10, 0, 0, 0);    \
    a11 = __builtin_amdgcn_mfma_f32_32x32x16_f16(x1, y1, a11, 0, 0, 0);    \
    __builtin_amdgcn_s_setprio(0);                                         \
  } while (0)

  for (int l = 0; l < NL; ++l) {
    f32x16 a00 = zz, a01 = zz, a10 = zz, a11 = zz;
    const int Pb = l << 5;               // layer base position

    #pragma unroll 1
    for (int t = 0; t < NKS/2; ++t) {
      const int i = 2*t;
      // prefetch A for sequence position i+1
      {
        const int kk = (i + 1 + ksr) & 31;
        const int co = ((kk << 5) + hoff) ^ rx;
        afB0 = *(const f16x8*)(arow0 + co);
        afB1 = *(const f16x8*)(arow1 + co);
      }
      MFMAQ(afA0, afA1, bfA0, bfA1);           // position i
      // reload bfA for position i+2 (may cross into next layer; clamp at tail)
      {
        int P = Pb + i + 2; if (P > NG2-1) P = NG2-1;
        const int G = (P & ~31) | ((P + ksr) & 31);
        const char* p = wb + ((size_t)G << 14);
        bfA0 = *(const f16x8*)(p);
        bfA1 = *(const f16x8*)(p + 1024);
      }
      // prefetch A for position i+2 (same layer only)
      if (t + 1 < NKS/2) {
        const int kk = (i + 2 + ksr) & 31;
        const int co = ((kk << 5) + hoff) ^ rx;
        afA0 = *(const f16x8*)(arow0 + co);
        afA1 = *(const f16x8*)(arow1 + co);
      }
      MFMAQ(afB0, afB1, bfB0, bfB1);           // position i+1
      {
        int P = Pb + i + 3; if (P > NG2-1) P = NG2-1;
        const int G = (P & ~31) | ((P + ksr) & 31);
        const char* p = wb + ((size_t)G << 14);
        bfB0 = *(const f16x8*)(p);
        bfB1 = *(const f16x8*)(p + 1024);
      }
    }
    __syncthreads();   // all A-reads of layer l complete before overwrite

    // ---- epilogue: h=(1+a)(dot+b); u'=sin h; du'=(1+a)cos(h)*dot_t ----
    // 32x32 C/D layout: col = lane&31, row = (r&3) + 8*(r>>2) + 4*(lane>>5)
    const float opa = 1.0f + alphas[l];
    #pragma unroll
    for (int Nt = 0; Nt < 2; ++Nt) {
      const int nc = wv*64 + Nt*32 + l31;
      const float bias = bs[l*NN + nc];
      #pragma unroll
      for (int Mt = 0; Mt < 2; ++Mt) {
        const f32x16 c = (Mt == 0) ? (Nt == 0 ? a00 : a01)
                                   : (Nt == 0 ? a10 : a11);
        #pragma unroll
        for (int j = 0; j < 4; ++j) {
          const float hh = opa * (c[4*j] + bias);
          const float un = __sinf(hh);
          const float fc = opa * __cosf(hh);
          const float vv[4] = { un, fc*c[4*j+1], fc*c[4*j+2], fc*c[4*j+3] };
          const int m0 = Mt*32 + 8*j + 4*kh;
          #pragma unroll
          for (int s = 0; s < 4; ++s) {
            const int m = m0 + s;
            *(uint16_t*)(smem + (size_t)m*1024 + ((2*nc) ^ ((m & 7)*16))) = f2h_bits(vv[s]);
          }
        }
      }
    }
    __syncthreads();

    if (l + 1 < NL) {   // preload sequence position 0 of next layer
      afA0 = *(const f16x8*)(arow0 + co0);
      afA1 = *(const f16x8*)(arow1 + co0);
    }
  }

  // ---- final projection: dp[m][o] = sum_k A[m][k]*Wf[k][o] * scale[o] ----
  float* dp = (float*)(smem + LDS_A);
  const float4 sc4 = *(const float4*)scl;
  for (int rr = 0; rr < MROWS/8; ++rr) {     // 8 rows per wave
    const int m = wv*(MROWS/8) + rr;
    float p0 = 0.f, p1 = 0.f, p2 = 0.f, p3 = 0.f;
    #pragma unroll
    for (int j = 0; j < 8; ++j) {
      const int k = lane + j*64;
      float a = h2f(*(const uint16_t*)(smem + (size_t)m*1024 + ((2*k) ^ ((m & 7)*16))));
      float4 wf = ((const float4*)Wf)[k];
      p0 += a*wf.x; p1 += a*wf.y; p2 += a*wf.z; p3 += a*wf.w;
    }
    #pragma unroll
    for (int d = 1; d < 64; d <<= 1) {
      p0 += __shfl_xor(p0, d, 64);
      p1 += __shfl_xor(p1, d, 64);
      p2 += __shfl_xor(p2, d, 64);
      p3 += __shfl_xor(p3, d, 64);
    }
    if (lane == 0) {
      float4* o = (float4*)(dp + m*4);
      *o = make_float4(p0*sc4.x, p1*sc4.y, p2*sc4.z, p3*sc4.w);
    }
  }
  __syncthreads();

  // rows 4s+1=dPdz, 4s+2=dPdx, 4s+3=dPdy
  // u = dPdy[2]-dPdz[1]+dPdx[3]; v = dPdz[0]-dPdx[2]+dPdy[3]; w = dPdx[1]-dPdy[0]+dPdz[3]
  if (tid < SPB*3) {
    const int sl = tid / 3, c = tid - sl*3;
    const float* d1 = dp + (sl*4 + 1)*4;
    const float* d2 = dp + (sl*4 + 2)*4;
    const float* d3 = dp + (sl*4 + 3)*4;
    float val;
    if (c == 0)      val = d3[2] - d1[1] + d2[3];
    else if (c == 1) val = d1[0] - d2[2] + d3[3];
    else             val = d2[1] - d3[0] + d1[3];
    out[(size_t)(sbase + sl)*3 + c] = val;
  }
}

extern "C" void kernel_launch(void* const* d_in, const int* in_sizes, int n_in,
                              void* d_out, int out_size, void* d_ws, size_t ws_size,
                              hipStream_t stream) {
  const float* inputs = (const float*)d_in[0];
  const float* Brff   = (const float*)d_in[1];
  const float* Ws     = (const float*)d_in[2];
  const float* bsp    = (const float*)d_in[3];
  const float* alph   = (const float*)d_in[4];
  const float* Wfp    = (const float*)d_in[5];
  const float* sclp   = (const float*)d_in[6];
  uint16_t* wimg = (uint16_t*)d_ws;           // needs 4 MiB workspace

  prep_weights<<<NG2, 512, 0, stream>>>(Ws, wimg);
  const int nblocks = B_SZ / SPB;             // 4096
  pinn_fused<<<nblocks, 512, LDS_TOTAL, stream>>>(inputs, Brff, bsp, alph, Wfp, sclp,
                                                  wimg, (float*)d_out);
}